// Round 20
// baseline (83.232 us; speedup 1.0000x reference)
//
#include <hip/hip_runtime.h>
#include <hip/hip_bf16.h>
#include <cstdint>

#define DIM   1024
#define HEADS 16
#define BB    32
#define NN    2048
#define DH    64
#define PARTS 8    // per-batch partitions (one block each)
#define TS    32   // slots per LDS tile

constexpr float SCALE = 0.03125f;  // 1/sqrt(1024)
constexpr float LN_EPS = 1e-5f;

typedef __attribute__((ext_vector_type(8))) short short8v;
typedef __attribute__((ext_vector_type(4))) short short4v;
typedef __attribute__((ext_vector_type(4))) float f32x4;

// Raw barrier: drains this wave's LDS ops (lgkmcnt) but leaves global prefetch
// loads (vmcnt) in flight across the barrier — __syncthreads() drains vmcnt(0).
#define BARRIER_LDS() do {                                         \
    asm volatile("s_waitcnt lgkmcnt(0)" ::: "memory");             \
    __builtin_amdgcn_s_barrier();                                  \
    asm volatile("" ::: "memory");                                 \
  } while (0)

__device__ __forceinline__ short f2bf(float f) {
  union { __hip_bfloat16 h; short s; } u;
  u.h = __float2bfloat16(f);
  return u.s;
}
__device__ __forceinline__ float bf2f(short s) {
  union { unsigned int i; float f; } u;
  u.i = ((unsigned int)(unsigned short)s) << 16;
  return u.f;
}
__device__ __forceinline__ short8v pack8(float4 a, float4 b) {
  short8v v;
  v[0] = f2bf(a.x); v[1] = f2bf(a.y); v[2] = f2bf(a.z); v[3] = f2bf(a.w);
  v[4] = f2bf(b.x); v[5] = f2bf(b.y); v[6] = f2bf(b.z); v[7] = f2bf(b.w);
  return v;
}

__device__ __forceinline__ float block_sum256(float v, volatile float* red) {
  #pragma unroll
  for (int off = 32; off; off >>= 1) v += __shfl_xor(v, off);
  __syncthreads();
  if ((threadIdx.x & 63) == 0) red[threadIdx.x >> 6] = v;
  __syncthreads();
  return red[0] + red[1] + red[2] + red[3];
}

// ---------------- K0a: blocks 0-31 index compaction; 32-159 Qp rows (Wq read exactly once) ----------------
__global__ void k_front1(const int* __restrict__ mask, const float* __restrict__ S,
                         const float* __restrict__ Wq, const float* __restrict__ bq,
                         float* __restrict__ Qp, int* __restrict__ idx,
                         int* __restrict__ cnt) {
  __shared__ int wsum[4];
  int tid = threadIdx.x;
  if (blockIdx.x < 32) {
    int b = blockIdx.x;
    const int* mb = mask + b * NN;
    int base = tid * 8;
    int loc[8], c = 0;
    #pragma unroll
    for (int i = 0; i < 8; ++i) { loc[i] = mb[base + i]; c += (loc[i] != 0); }
    int pre = c;
    #pragma unroll
    for (int off = 1; off < 64; off <<= 1) {
      int y = __shfl_up(pre, off);
      if ((tid & 63) >= off) pre += y;
    }
    if ((tid & 63) == 63) wsum[tid >> 6] = pre;
    __syncthreads();
    int wo = 0;
    for (int wv = 0; wv < (tid >> 6); ++wv) wo += wsum[wv];
    int pos = wo + pre - c;
    int* ib = idx + b * NN;
    #pragma unroll
    for (int i = 0; i < 8; ++i) if (loc[i]) ib[pos++] = base + i;
    if (tid == 255) cnt[b] = wo + pre;
    return;
  }
  // Qp: block q computes rows q*8..q*8+7; 32 threads per row
  int q = blockIdx.x - 32;              // 0..127
  int rgrp = tid >> 5, l32 = tid & 31;
  int d = q * 8 + rgrp;
  const float* wr = Wq + (size_t)d * DIM + l32 * 4;
  const float* sp = S + l32 * 4;
  float a = 0.f;
  #pragma unroll
  for (int k = 0; k < 8; ++k) {
    float4 av = *(const float4*)(wr + k * 128);
    float4 sv = *(const float4*)(sp + k * 128);
    a += av.x * sv.x + av.y * sv.y + av.z * sv.z + av.w * sv.w;
  }
  #pragma unroll
  for (int off = 16; off; off >>= 1) a += __shfl_xor(a, off);
  if (l32 == 0) Qp[d] = a + bq[d];
}

// ---------------- K0b: qk_bf[h][c] (bf16, pre-swizzled) + qb[h]; grid 128 = 16h x 8cblk, 128 thr ----------------
__global__ void k_front2(const float* __restrict__ Qp, const float* __restrict__ Wk,
                         const float* __restrict__ bk, short* __restrict__ qk_bf,
                         float* __restrict__ qb) {
  __shared__ float qpl[DH];
  int tid = threadIdx.x;
  int h = blockIdx.x >> 3, cblk = blockIdx.x & 7;
  if (tid < DH) qpl[tid] = Qp[h * DH + tid];
  __syncthreads();
  if (cblk == 0 && tid < 64) {          // qb[h] = Qp[h,:] . bk[h,:]
    float v = qpl[tid] * bk[h * DH + tid];
    #pragma unroll
    for (int off = 32; off; off >>= 1) v += __shfl_xor(v, off);
    if (tid == 0) qb[h] = v;
  }
  int c = cblk * 128 + tid;
  float acc = 0.f;
  #pragma unroll 8
  for (int d0 = 0; d0 < DH; ++d0)
    acc += qpl[d0] * Wk[(size_t)(h * DH + d0) * DIM + c];
  int slot = (c >> 3) ^ (h & 7);        // qlds swizzle
  qk_bf[h * 1024 + slot * 8 + (c & 7)] = f2bf(acc);
}

#define LOADSET(pfA_, pfB_, tt)                                            \
  { int tbL = pstart + (tt) * TS;                                          \
    _Pragma("unroll")                                                      \
    for (int k = 0; k < 8; ++k) {                                          \
      int i = tid + k * 512;                                               \
      int row = i >> 7, c8 = i & 127;                                      \
      int sl = tbL + row; if (sl >= pend) sl = pend - 1;                   \
      int n = ib[sl];                                                      \
      const float4* xg = (const float4*)(Xb + (size_t)n * DIM + c8 * 8);   \
      pfA_[k] = xg[0]; pfB_[k] = xg[1];                                    \
    } }

#define WRITESET(pfA_, pfB_)                                               \
  { _Pragma("unroll")                                                      \
    for (int k = 0; k < 8; ++k) {                                          \
      int i = tid + k * 512;                                               \
      int row = i >> 7, c8 = i & 127;                                      \
      int sw = c8 ^ (row & 7) ^ ((row >> 3) << 3);                         \
      *(short8v*)(xlds + row * 1024 + sw * 8) = pack8(pfA_[k], pfB_[k]);   \
    } }

// ---------------- K1: flash-fused attention, no-max softmax, lgkm-only barriers ----------------
// r16 structure; prefetch issued right after WRITESET and kept in flight across all barriers.
__global__ __launch_bounds__(512, 1) void k_fused11(const float* __restrict__ X,
                                                    const short* __restrict__ qk_bf,
                                                    const float* __restrict__ qb,
                                                    const int* __restrict__ idx,
                                                    const int* __restrict__ cnt,
                                                    short* __restrict__ Zt,
                                                    float* __restrict__ lt_g) {
  __shared__ short qlds[HEADS * 1024];   // 32 KB bf16, swizzle: slot = c8 ^ (h&7)
  __shared__ short xlds[TS * 1024];      // 64 KB bf16, swizzle: slot = c8 ^ (s&7) ^ ((s>>3)<<3)
  __shared__ __align__(16) short elbf[HEADS * 40];     // E[h][s] bf16, stride 40
  __shared__ __align__(16) short zst[HEADS * 1040];    // 32.5 KB: Z staging for coalesced out
  __shared__ float lt_l[32];
  int tid = threadIdx.x;
  int b = blockIdx.x >> 3, p = blockIdx.x & 7;
  int count = cnt[b];
  int chunk = (count + PARTS - 1) / PARTS;
  int pstart = p * chunk;
  int pend = pstart + chunk; if (pend > count) pend = count;
  int len = pend - pstart;
  int ntsub = (len + TS - 1) / TS;       // uniform per block
  {
    const short8v* qg = (const short8v*)qk_bf;
    short8v* ql = (short8v*)qlds;
    #pragma unroll
    for (int i = 0; i < 4; ++i) ql[tid + i * 512] = qg[tid + i * 512];
  }
  int wv = tid >> 6, lane = tid & 63;
  int r16 = lane & 15, kg = lane >> 4;
  int hx = r16 & 7;
  const int* ib = idx + b * NN;
  const float* Xb = X + (size_t)b * NN * DIM;
  const short* qrow = qlds + r16 * 1024;
  float qbv = qb[r16];
  int srow = wv * 16 + r16;                       // QK^T A row (waves 0-1)
  int axor = (srow & 7) ^ (((srow >> 3) & 3) << 3);
  f32x4 acc[8];
  #pragma unroll
  for (int blk = 0; blk < 8; ++blk) acc[blk] = (f32x4){0.f, 0.f, 0.f, 0.f};
  float lrun_reg = 0.f;                  // per-head running sum (threads 0-15)
  float4 pfA[8], pfB[8];
  // initial prefetch (t=0)
  if (ntsub > 0) LOADSET(pfA, pfB, 0)
  BARRIER_LDS();                         // qlds visible (t=0 prefetch stays in flight)

  for (int t = 0; t < ntsub; ++t) {
    int tb = pstart + t * TS;
    BARRIER_LDS();                       // S0: prev tile's xlds/elbf readers done
    // ---- write prefetched X tile -> xlds (vmcnt wait on pf use, compiler-inserted) ----
    WRITESET(pfA, pfB)
    // ---- issue prefetch for t+1 at the earliest point; stays in flight across S1/S3/S0 ----
    if (t + 1 < ntsub) LOADSET(pfA, pfB, t + 1)
    BARRIER_LDS();                       // S1: xlds ready
    // ---- QK^T (waves 0-1) + direct exp (no max shift): e = exp((qa+qb)*SCALE) ----
    if (wv < 2) {
      const short* arow = xlds + srow * 1024;
      f32x4 qa = {0.f, 0.f, 0.f, 0.f};
      #pragma unroll 8
      for (int m = 0; m < 32; ++m) {
        int c8 = 4 * m + kg;
        short8v af = *(const short8v*)(arow + ((c8 ^ axor) << 3));
        short8v bf = *(const short8v*)(qrow + ((c8 ^ hx) << 3));
        qa = __builtin_amdgcn_mfma_f32_16x16x32_bf16(af, bf, qa, 0, 0, 0);
      }
      float es = 0.f;
      #pragma unroll
      for (int j = 0; j < 4; ++j) {
        int slot = tb + wv * 16 + kg * 4 + j;
        float e = (slot < pend) ? __expf((qa[j] + qbv) * SCALE) : 0.f;
        elbf[r16 * 40 + (wv * 16 + kg * 4 + j)] = f2bf(e);
        es += e;
      }
      es += __shfl_xor(es, 16);
      es += __shfl_xor(es, 32);
      if (kg == 0) lt_l[wv * 16 + r16] = es;
    }
    BARRIER_LDS();                       // S3: elbf, lt_l ready
    // ---- phase C (all 8 waves, MFMA): Z[h][c] += E[h][s] * X[s][c] over s=0..31 ----
    {
      int g = kg;                        // lane>>4
      short8v ea = *(const short8v*)(elbf + r16 * 40 + g * 8);
      #pragma unroll
      for (int blk = 0; blk < 8; ++blk) {
        int c = wv * 128 + blk * 16 + r16;
        int ch = c >> 3, cl = c & 7;
        short8v xb;
        #pragma unroll
        for (int u = 0; u < 8; ++u) {
          int s = g * 8 + u;
          int sw = ch ^ (s & 7) ^ ((s >> 3) << 3);
          xb[u] = xlds[s * 1024 + sw * 8 + cl];
        }
        acc[blk] = __builtin_amdgcn_mfma_f32_16x16x32_bf16(ea, xb, acc[blk], 0, 0, 0);
      }
      if (tid < 16) lrun_reg += lt_l[tid] + lt_l[16 + tid];
    }
  }
  // ---- epilogue ----
  if (tid < 16) lt_g[(b * PARTS + p) * HEADS + tid] = lrun_reg;
  // acc -> zst (D layout: row h = kg*4+j, col c = wv*128+blk*16+r16)
  #pragma unroll
  for (int blk = 0; blk < 8; ++blk) {
    int c = wv * 128 + blk * 16 + r16;
    #pragma unroll
    for (int j = 0; j < 4; ++j)
      zst[(kg * 4 + j) * 1040 + c] = f2bf(acc[blk][j]);
  }
  __syncthreads();
  short* zbase = Zt + ((size_t)(b * PARTS + p) * HEADS) * DIM;
  #pragma unroll
  for (int it = 0; it < 8; ++it) {
    int e4 = it * 2048 + tid * 4;
    int h = e4 >> 10, c = e4 & 1023;
    *(short4v*)(zbase + h * DIM + c) = *(const short4v*)(zst + h * 1040 + c);
  }
}

// ---------------- K2: reduce parts (plain sum / L) + Wv projection ----------------
__global__ __launch_bounds__(256) void k_tov3(const short* __restrict__ Zt,
                                              const float* __restrict__ lt_g,
                                              const float* __restrict__ Wv,
                                              float* __restrict__ T,
                                              float* __restrict__ lsum) {
  int b = blockIdx.x >> 4, h = blockIdx.x & 15;   // grid 512
  int tid = threadIdx.x;
  __shared__ float zlds[DIM];
  float L = 0.f;
  #pragma unroll
  for (int t = 0; t < PARTS; ++t) L += lt_g[(b * PARTS + t) * HEADS + h];
  float inv = L > 0.f ? 1.f / L : 0.f;
  float4 zs = make_float4(0.f, 0.f, 0.f, 0.f);
  #pragma unroll
  for (int t = 0; t < PARTS; ++t) {
    short4v z4 = *(const short4v*)(Zt + ((size_t)(b * PARTS + t) * HEADS + h) * DIM + tid * 4);
    zs.x += bf2f(z4[0]); zs.y += bf2f(z4[1]);
    zs.z += bf2f(z4[2]); zs.w += bf2f(z4[3]);
  }
  zs.x *= inv; zs.y *= inv; zs.z *= inv; zs.w *= inv;
  *(float4*)(zlds + tid * 4) = zs;
  __syncthreads();
  int wv = tid >> 6, lane = tid & 63;
  float4 zr[4];
  #pragma unroll
  for (int j = 0; j < 4; ++j) zr[j] = *(const float4*)(zlds + lane * 4 + j * 256);
  for (int i = 0; i < 16; ++i) {
    int df = h * 64 + wv * 16 + i;
    const float* wr = Wv + (size_t)df * DIM + lane * 4;
    float a = 0.f;
    #pragma unroll
    for (int j = 0; j < 4; ++j) {
      float4 w4 = *(const float4*)(wr + j * 256);
      a += zr[j].x * w4.x + zr[j].y * w4.y + zr[j].z * w4.z + zr[j].w * w4.w;
    }
    #pragma unroll
    for (int off = 32; off; off >>= 1) a += __shfl_xor(a, off);
    if (lane == 0) T[(size_t)b * DIM + df] = a;
  }
  if (tid == 0) lsum[b * HEADS + h] = L > 0.f ? 1.f : 0.f;
}

// ---------------- K3: U = LN0(S + T + l*bv) ----------------
__global__ void k_ln0(const float* __restrict__ S, const float* __restrict__ T,
                      const float* __restrict__ lsum, const float* __restrict__ bv,
                      const float* __restrict__ g0, const float* __restrict__ b0,
                      float* __restrict__ U) {
  __shared__ float red[4];
  int b = blockIdx.x, tid = threadIdx.x, d0 = tid * 4;   // grid 32
  float4 s4 = *(const float4*)(S + d0);
  float4 t4 = *(const float4*)(T + (size_t)b * DIM + d0);
  float4 v4 = *(const float4*)(bv + d0);
  float lh = lsum[b * HEADS + (d0 >> 6)];
  float x0 = s4.x + t4.x + lh * v4.x;
  float x1 = s4.y + t4.y + lh * v4.y;
  float x2 = s4.z + t4.z + lh * v4.z;
  float x3 = s4.w + t4.w + lh * v4.w;
  float mu = block_sum256(x0 + x1 + x2 + x3, red) * (1.f / DIM);
  float e0 = x0 - mu, e1 = x1 - mu, e2 = x2 - mu, e3 = x3 - mu;
  float var = block_sum256(e0 * e0 + e1 * e1 + e2 * e2 + e3 * e3, red) * (1.f / DIM);
  float r = rsqrtf(var + LN_EPS);
  float4 g4 = *(const float4*)(g0 + d0);
  float4 bb4 = *(const float4*)(b0 + d0);
  float4 o;
  o.x = e0 * r * g4.x + bb4.x;
  o.y = e1 * r * g4.y + bb4.y;
  o.z = e2 * r * g4.z + bb4.z;
  o.w = e3 * r * g4.w + bb4.w;
  *(float4*)(U + (size_t)b * DIM + d0) = o;
}

// ---------------- K4: R = relu(U . Wo^T + bo) ----------------
__global__ void k_wo(const float* __restrict__ U, const float* __restrict__ Wo,
                     const float* __restrict__ bo, float* __restrict__ R) {
  int wave = threadIdx.x >> 6, lane = threadIdx.x & 63;
  int dfb = blockIdx.x;                       // grid 256
  for (int dot = wave; dot < 128; dot += 4) {
    int b = dot >> 2, dfl = dot & 3;
    int df = dfb * 4 + dfl;
    const float* wr = Wo + (size_t)df * DIM + lane * 4;
    const float* ur = U + (size_t)b * DIM + lane * 4;
    float acc = 0.f;
    #pragma unroll
    for (int k = 0; k < 4; ++k) {
      float4 a = *(const float4*)(wr + k * 256);
      float4 u = *(const float4*)(ur + k * 256);
      acc += a.x * u.x + a.y * u.y + a.z * u.z + a.w * u.w;
    }
    #pragma unroll
    for (int off = 32; off; off >>= 1) acc += __shfl_xor(acc, off);
    if (lane == 0) R[(size_t)b * DIM + df] = fmaxf(acc + bo[df], 0.f);
  }
}

// ---------------- K5: out = LN1(U + R) ----------------
__global__ void k_ln1(const float* __restrict__ U, const float* __restrict__ R,
                      const float* __restrict__ g1, const float* __restrict__ b1,
                      float* __restrict__ out) {
  __shared__ float red[4];
  int b = blockIdx.x, tid = threadIdx.x, d0 = tid * 4;   // grid 32
  float4 u4 = *(const float4*)(U + (size_t)b * DIM + d0);
  float4 r4 = *(const float4*)(R + (size_t)b * DIM + d0);
  float x0 = u4.x + r4.x, x1 = u4.y + r4.y, x2 = u4.z + r4.z, x3 = u4.w + r4.w;
  float mu = block_sum256(x0 + x1 + x2 + x3, red) * (1.f / DIM);
  float e0 = x0 - mu, e1 = x1 - mu, e2 = x2 - mu, e3 = x3 - mu;
  float var = block_sum256(e0 * e0 + e1 * e1 + e2 * e2 + e3 * e3, red) * (1.f / DIM);
  float r = rsqrtf(var + LN_EPS);
  float4 g4 = *(const float4*)(g1 + d0);
  float4 bb4 = *(const float4*)(b1 + d0);
  float4 o;
  o.x = e0 * r * g4.x + bb4.x;
  o.y = e1 * r * g4.y + bb4.y;
  o.z = e2 * r * g4.z + bb4.z;
  o.w = e3 * r * g4.w + bb4.w;
  *(float4*)(out + (size_t)b * DIM + d0) = o;
}

extern "C" void kernel_launch(void* const* d_in, const int* in_sizes, int n_in,
                              void* d_out, int out_size, void* d_ws, size_t ws_size,
                              hipStream_t stream) {
  (void)in_sizes; (void)n_in; (void)out_size; (void)ws_size;
  const float* X  = (const float*)d_in[0];
  const int*   mask = (const int*)d_in[1];
  const float* S  = (const float*)d_in[2];
  const float* Wq = (const float*)d_in[3];
  const float* bq = (const float*)d_in[4];
  const float* Wk = (const float*)d_in[5];
  const float* bk = (const float*)d_in[6];
  const float* Wv = (const float*)d_in[7];
  const float* bv = (const float*)d_in[8];
  const float* Wo = (const float*)d_in[9];
  const float* bo = (const float*)d_in[10];
  const float* g0 = (const float*)d_in[11];
  const float* b0 = (const float*)d_in[12];
  const float* g1 = (const float*)d_in[13];
  const float* b1 = (const float*)d_in[14];
  float* out = (float*)d_out;

  char* base  = (char*)d_ws;
  size_t off = 0;
  short* Zt   = (short*)(base + off); off += (size_t)BB * PARTS * HEADS * DIM * 2;  // 8.4 MB
  short* qkbf = (short*)(base + off); off += HEADS * 1024 * 2;                      // 32 KB
  float* qb   = (float*)(base + off); off += 64;
  float* lt   = (float*)(base + off); off += (size_t)BB * PARTS * HEADS * 4;        // 16 KB
  float* lsum = (float*)(base + off); off += BB * HEADS * 4;
  int*   idx  = (int*)(base + off);   off += (size_t)BB * NN * 4;                   // 256 KB
  int*   cnt  = (int*)(base + off);   off += 256;
  float* Qp   = (float*)(base + off); off += DIM * 4;
  float* T    = (float*)(base + off); off += (size_t)BB * DIM * 4;
  float* U    = (float*)(base + off); off += (size_t)BB * DIM * 4;
  float* R    = (float*)(base + off); off += (size_t)BB * DIM * 4;

  k_front1 <<<160, 256, 0, stream>>>(mask, S, Wq, bq, Qp, idx, cnt);
  k_front2 <<<128, 128, 0, stream>>>(Qp, Wk, bk, qkbf, qb);
  k_fused11<<<256, 512, 0, stream>>>(X, qkbf, qb, idx, cnt, Zt, lt);
  k_tov3   <<<512, 256, 0, stream>>>(Zt, lt, Wv, T, lsum);
  k_ln0    <<<32,  256, 0, stream>>>(S, T, lsum, bv, g0, b0, U);
  k_wo     <<<256, 256, 0, stream>>>(U, Wo, bo, R);
  k_ln1    <<<32,  256, 0, stream>>>(U, R, g1, b1, out);
}

// Round 21
// 80.777 us; speedup vs baseline: 1.0304x; 1.0304x over previous
//
#include <hip/hip_runtime.h>
#include <hip/hip_bf16.h>
#include <cstdint>

#define DIM   1024
#define HEADS 16
#define BB    32
#define NN    2048
#define DH    64
#define PARTS 8    // per-batch partitions (one block each)
#define TS    32   // slots per LDS tile

constexpr float SCALE = 0.03125f;  // 1/sqrt(1024)
constexpr float LN_EPS = 1e-5f;

typedef __attribute__((ext_vector_type(8))) short short8v;
typedef __attribute__((ext_vector_type(4))) short short4v;
typedef __attribute__((ext_vector_type(4))) float f32x4;

__device__ __forceinline__ short f2bf(float f) {
  union { __hip_bfloat16 h; short s; } u;
  u.h = __float2bfloat16(f);
  return u.s;
}
__device__ __forceinline__ float bf2f(short s) {
  union { unsigned int i; float f; } u;
  u.i = ((unsigned int)(unsigned short)s) << 16;
  return u.f;
}
__device__ __forceinline__ short8v pack8(float4 a, float4 b) {
  short8v v;
  v[0] = f2bf(a.x); v[1] = f2bf(a.y); v[2] = f2bf(a.z); v[3] = f2bf(a.w);
  v[4] = f2bf(b.x); v[5] = f2bf(b.y); v[6] = f2bf(b.z); v[7] = f2bf(b.w);
  return v;
}

__device__ __forceinline__ float block_sum256(float v, volatile float* red) {
  #pragma unroll
  for (int off = 32; off; off >>= 1) v += __shfl_xor(v, off);
  __syncthreads();
  if ((threadIdx.x & 63) == 0) red[threadIdx.x >> 6] = v;
  __syncthreads();
  return red[0] + red[1] + red[2] + red[3];
}

// ---------------- K0a: blocks 0-31 index compaction; 32-159 Qp rows (Wq read exactly once) ----------------
__global__ void k_front1(const int* __restrict__ mask, const float* __restrict__ S,
                         const float* __restrict__ Wq, const float* __restrict__ bq,
                         float* __restrict__ Qp, int* __restrict__ idx,
                         int* __restrict__ cnt) {
  __shared__ int wsum[4];
  int tid = threadIdx.x;
  if (blockIdx.x < 32) {
    int b = blockIdx.x;
    const int* mb = mask + b * NN;
    int base = tid * 8;
    int loc[8], c = 0;
    #pragma unroll
    for (int i = 0; i < 8; ++i) { loc[i] = mb[base + i]; c += (loc[i] != 0); }
    int pre = c;
    #pragma unroll
    for (int off = 1; off < 64; off <<= 1) {
      int y = __shfl_up(pre, off);
      if ((tid & 63) >= off) pre += y;
    }
    if ((tid & 63) == 63) wsum[tid >> 6] = pre;
    __syncthreads();
    int wo = 0;
    for (int wv = 0; wv < (tid >> 6); ++wv) wo += wsum[wv];
    int pos = wo + pre - c;
    int* ib = idx + b * NN;
    #pragma unroll
    for (int i = 0; i < 8; ++i) if (loc[i]) ib[pos++] = base + i;
    if (tid == 255) cnt[b] = wo + pre;
    return;
  }
  // Qp: block q computes rows q*8..q*8+7; 32 threads per row
  int q = blockIdx.x - 32;              // 0..127
  int rgrp = tid >> 5, l32 = tid & 31;
  int d = q * 8 + rgrp;
  const float* wr = Wq + (size_t)d * DIM + l32 * 4;
  const float* sp = S + l32 * 4;
  float a = 0.f;
  #pragma unroll
  for (int k = 0; k < 8; ++k) {
    float4 av = *(const float4*)(wr + k * 128);
    float4 sv = *(const float4*)(sp + k * 128);
    a += av.x * sv.x + av.y * sv.y + av.z * sv.z + av.w * sv.w;
  }
  #pragma unroll
  for (int off = 16; off; off >>= 1) a += __shfl_xor(a, off);
  if (l32 == 0) Qp[d] = a + bq[d];
}

// ---------------- K0b: qk_bf[h][c] (bf16, pre-swizzled) + qb[h]; grid 128 = 16h x 8cblk, 128 thr ----------------
__global__ void k_front2(const float* __restrict__ Qp, const float* __restrict__ Wk,
                         const float* __restrict__ bk, short* __restrict__ qk_bf,
                         float* __restrict__ qb) {
  __shared__ float qpl[DH];
  int tid = threadIdx.x;
  int h = blockIdx.x >> 3, cblk = blockIdx.x & 7;
  if (tid < DH) qpl[tid] = Qp[h * DH + tid];
  __syncthreads();
  if (cblk == 0 && tid < 64) {          // qb[h] = Qp[h,:] . bk[h,:]
    float v = qpl[tid] * bk[h * DH + tid];
    #pragma unroll
    for (int off = 32; off; off >>= 1) v += __shfl_xor(v, off);
    if (tid == 0) qb[h] = v;
  }
  int c = cblk * 128 + tid;
  float acc = 0.f;
  #pragma unroll 8
  for (int d0 = 0; d0 < DH; ++d0)
    acc += qpl[d0] * Wk[(size_t)(h * DH + d0) * DIM + c];
  int slot = (c >> 3) ^ (h & 7);        // qlds swizzle
  qk_bf[h * 1024 + slot * 8 + (c & 7)] = f2bf(acc);
}

#define LOADSET(pfA_, pfB_, tt)                                            \
  { int tbL = pstart + (tt) * TS;                                          \
    _Pragma("unroll")                                                      \
    for (int k = 0; k < 8; ++k) {                                          \
      int i = tid + k * 512;                                               \
      int row = i >> 7, c8 = i & 127;                                      \
      int sl = tbL + row; if (sl >= pend) sl = pend - 1;                   \
      int n = ib[sl];                                                      \
      const float4* xg = (const float4*)(Xb + (size_t)n * DIM + c8 * 8);   \
      pfA_[k] = xg[0]; pfB_[k] = xg[1];                                    \
    } }

#define WRITESET(pfA_, pfB_)                                               \
  { _Pragma("unroll")                                                      \
    for (int k = 0; k < 8; ++k) {                                          \
      int i = tid + k * 512;                                               \
      int row = i >> 7, c8 = i & 127;                                      \
      int sw = c8 ^ (row & 7) ^ ((row >> 3) << 3);                         \
      *(short8v*)(xlds + row * 1024 + sw * 8) = pack8(pfA_[k], pfB_[k]);   \
    } }

// ---------------- K1: flash-fused attention, NO-MAX softmax (scores ~|s|<0.1, exp exact) ----------------
// Per tile: 3 barriers (S0/S1/S3), no rescale in phase C; 1-deep register prefetch.
__global__ __launch_bounds__(512, 1) void k_fused8(const float* __restrict__ X,
                                                   const short* __restrict__ qk_bf,
                                                   const float* __restrict__ qb,
                                                   const int* __restrict__ idx,
                                                   const int* __restrict__ cnt,
                                                   short* __restrict__ Zt,
                                                   float* __restrict__ lt_g) {
  __shared__ short qlds[HEADS * 1024];   // 32 KB bf16, swizzle: slot = c8 ^ (h&7)
  __shared__ short xlds[TS * 1024];      // 64 KB bf16, swizzle: slot = c8 ^ (s&7) ^ ((s>>3)<<3)
  __shared__ __align__(16) short elbf[HEADS * 40];     // E[h][s] bf16, stride 40
  __shared__ __align__(16) short zst[HEADS * 1040];    // 32.5 KB: Z staging for coalesced out
  __shared__ float lt_l[32];
  int tid = threadIdx.x;
  int b = blockIdx.x >> 3, p = blockIdx.x & 7;
  int count = cnt[b];
  int chunk = (count + PARTS - 1) / PARTS;
  int pstart = p * chunk;
  int pend = pstart + chunk; if (pend > count) pend = count;
  int len = pend - pstart;
  int ntsub = (len + TS - 1) / TS;       // uniform per block
  {
    const short8v* qg = (const short8v*)qk_bf;
    short8v* ql = (short8v*)qlds;
    #pragma unroll
    for (int i = 0; i < 4; ++i) ql[tid + i * 512] = qg[tid + i * 512];
  }
  int wv = tid >> 6, lane = tid & 63;
  int r16 = lane & 15, kg = lane >> 4;
  int hx = r16 & 7;
  const int* ib = idx + b * NN;
  const float* Xb = X + (size_t)b * NN * DIM;
  const short* qrow = qlds + r16 * 1024;
  float qbv = qb[r16];
  int srow = wv * 16 + r16;                       // QK^T A row (waves 0-1)
  int axor = (srow & 7) ^ (((srow >> 3) & 3) << 3);
  f32x4 acc[8];
  #pragma unroll
  for (int blk = 0; blk < 8; ++blk) acc[blk] = (f32x4){0.f, 0.f, 0.f, 0.f};
  float lrun_reg = 0.f;                  // per-head running sum (threads 0-15)
  float4 pfA[8], pfB[8];
  // initial prefetch (t=0)
  if (ntsub > 0) LOADSET(pfA, pfB, 0)
  __syncthreads();                       // qlds visible

  for (int t = 0; t < ntsub; ++t) {
    int tb = pstart + t * TS;
    __syncthreads();                     // S0: prev tile's xlds/elbf readers done
    // ---- write prefetched X tile -> xlds ----
    WRITESET(pfA, pfB)
    __syncthreads();                     // S1: xlds ready
    // ---- issue prefetch for t+1 ----
    if (t + 1 < ntsub) LOADSET(pfA, pfB, t + 1)
    // ---- QK^T (waves 0-1) + direct exp (no max shift): e = exp((qa+qb)*SCALE) ----
    if (wv < 2) {
      const short* arow = xlds + srow * 1024;
      f32x4 qa = {0.f, 0.f, 0.f, 0.f};
      #pragma unroll 8
      for (int m = 0; m < 32; ++m) {
        int c8 = 4 * m + kg;
        short8v af = *(const short8v*)(arow + ((c8 ^ axor) << 3));
        short8v bf = *(const short8v*)(qrow + ((c8 ^ hx) << 3));
        qa = __builtin_amdgcn_mfma_f32_16x16x32_bf16(af, bf, qa, 0, 0, 0);
      }
      float es = 0.f;
      #pragma unroll
      for (int j = 0; j < 4; ++j) {
        int slot = tb + wv * 16 + kg * 4 + j;
        float e = (slot < pend) ? __expf((qa[j] + qbv) * SCALE) : 0.f;
        elbf[r16 * 40 + (wv * 16 + kg * 4 + j)] = f2bf(e);
        es += e;
      }
      es += __shfl_xor(es, 16);
      es += __shfl_xor(es, 32);
      if (kg == 0) lt_l[wv * 16 + r16] = es;
    }
    __syncthreads();                     // S3: elbf, lt_l ready
    // ---- phase C (all 8 waves, MFMA): Z[h][c] += E[h][s] * X[s][c] over s=0..31 (no rescale) ----
    {
      int g = kg;                        // lane>>4
      short8v ea = *(const short8v*)(elbf + r16 * 40 + g * 8);
      #pragma unroll
      for (int blk = 0; blk < 8; ++blk) {
        int c = wv * 128 + blk * 16 + r16;
        int ch = c >> 3, cl = c & 7;
        short8v xb;
        #pragma unroll
        for (int u = 0; u < 8; ++u) {
          int s = g * 8 + u;
          int sw = ch ^ (s & 7) ^ ((s >> 3) << 3);
          xb[u] = xlds[s * 1024 + sw * 8 + cl];
        }
        acc[blk] = __builtin_amdgcn_mfma_f32_16x16x32_bf16(ea, xb, acc[blk], 0, 0, 0);
      }
      if (tid < 16) lrun_reg += lt_l[tid] + lt_l[16 + tid];
    }
  }
  // ---- epilogue ----
  if (tid < 16) lt_g[(b * PARTS + p) * HEADS + tid] = lrun_reg;
  // acc -> zst (D layout: row h = kg*4+j, col c = wv*128+blk*16+r16)
  #pragma unroll
  for (int blk = 0; blk < 8; ++blk) {
    int c = wv * 128 + blk * 16 + r16;
    #pragma unroll
    for (int j = 0; j < 4; ++j)
      zst[(kg * 4 + j) * 1040 + c] = f2bf(acc[blk][j]);
  }
  __syncthreads();
  short* zbase = Zt + ((size_t)(b * PARTS + p) * HEADS) * DIM;
  #pragma unroll
  for (int it = 0; it < 8; ++it) {
    int e4 = it * 2048 + tid * 4;
    int h = e4 >> 10, c = e4 & 1023;
    *(short4v*)(zbase + h * DIM + c) = *(const short4v*)(zst + h * 1040 + c);
  }
}

// ---------------- K2: reduce parts (plain sum / L) + Wv projection ----------------
__global__ __launch_bounds__(256) void k_tov3(const short* __restrict__ Zt,
                                              const float* __restrict__ lt_g,
                                              const float* __restrict__ Wv,
                                              float* __restrict__ T,
                                              float* __restrict__ lsum) {
  int b = blockIdx.x >> 4, h = blockIdx.x & 15;   // grid 512
  int tid = threadIdx.x;
  __shared__ float zlds[DIM];
  float L = 0.f;
  #pragma unroll
  for (int t = 0; t < PARTS; ++t) L += lt_g[(b * PARTS + t) * HEADS + h];
  float inv = L > 0.f ? 1.f / L : 0.f;
  float4 zs = make_float4(0.f, 0.f, 0.f, 0.f);
  #pragma unroll
  for (int t = 0; t < PARTS; ++t) {
    short4v z4 = *(const short4v*)(Zt + ((size_t)(b * PARTS + t) * HEADS + h) * DIM + tid * 4);
    zs.x += bf2f(z4[0]); zs.y += bf2f(z4[1]);
    zs.z += bf2f(z4[2]); zs.w += bf2f(z4[3]);
  }
  zs.x *= inv; zs.y *= inv; zs.z *= inv; zs.w *= inv;
  *(float4*)(zlds + tid * 4) = zs;
  __syncthreads();
  int wv = tid >> 6, lane = tid & 63;
  float4 zr[4];
  #pragma unroll
  for (int j = 0; j < 4; ++j) zr[j] = *(const float4*)(zlds + lane * 4 + j * 256);
  for (int i = 0; i < 16; ++i) {
    int df = h * 64 + wv * 16 + i;
    const float* wr = Wv + (size_t)df * DIM + lane * 4;
    float a = 0.f;
    #pragma unroll
    for (int j = 0; j < 4; ++j) {
      float4 w4 = *(const float4*)(wr + j * 256);
      a += zr[j].x * w4.x + zr[j].y * w4.y + zr[j].z * w4.z + zr[j].w * w4.w;
    }
    #pragma unroll
    for (int off = 32; off; off >>= 1) a += __shfl_xor(a, off);
    if (lane == 0) T[(size_t)b * DIM + df] = a;
  }
  if (tid == 0) lsum[b * HEADS + h] = L > 0.f ? 1.f : 0.f;
}

// ---------------- K3: U = LN0(S + T + l*bv) ----------------
__global__ void k_ln0(const float* __restrict__ S, const float* __restrict__ T,
                      const float* __restrict__ lsum, const float* __restrict__ bv,
                      const float* __restrict__ g0, const float* __restrict__ b0,
                      float* __restrict__ U) {
  __shared__ float red[4];
  int b = blockIdx.x, tid = threadIdx.x, d0 = tid * 4;   // grid 32
  float4 s4 = *(const float4*)(S + d0);
  float4 t4 = *(const float4*)(T + (size_t)b * DIM + d0);
  float4 v4 = *(const float4*)(bv + d0);
  float lh = lsum[b * HEADS + (d0 >> 6)];
  float x0 = s4.x + t4.x + lh * v4.x;
  float x1 = s4.y + t4.y + lh * v4.y;
  float x2 = s4.z + t4.z + lh * v4.z;
  float x3 = s4.w + t4.w + lh * v4.w;
  float mu = block_sum256(x0 + x1 + x2 + x3, red) * (1.f / DIM);
  float e0 = x0 - mu, e1 = x1 - mu, e2 = x2 - mu, e3 = x3 - mu;
  float var = block_sum256(e0 * e0 + e1 * e1 + e2 * e2 + e3 * e3, red) * (1.f / DIM);
  float r = rsqrtf(var + LN_EPS);
  float4 g4 = *(const float4*)(g0 + d0);
  float4 bb4 = *(const float4*)(b0 + d0);
  float4 o;
  o.x = e0 * r * g4.x + bb4.x;
  o.y = e1 * r * g4.y + bb4.y;
  o.z = e2 * r * g4.z + bb4.z;
  o.w = e3 * r * g4.w + bb4.w;
  *(float4*)(U + (size_t)b * DIM + d0) = o;
}

// ---------------- K4: R = relu(U . Wo^T + bo) ----------------
__global__ void k_wo(const float* __restrict__ U, const float* __restrict__ Wo,
                     const float* __restrict__ bo, float* __restrict__ R) {
  int wave = threadIdx.x >> 6, lane = threadIdx.x & 63;
  int dfb = blockIdx.x;                       // grid 256
  for (int dot = wave; dot < 128; dot += 4) {
    int b = dot >> 2, dfl = dot & 3;
    int df = dfb * 4 + dfl;
    const float* wr = Wo + (size_t)df * DIM + lane * 4;
    const float* ur = U + (size_t)b * DIM + lane * 4;
    float acc = 0.f;
    #pragma unroll
    for (int k = 0; k < 4; ++k) {
      float4 a = *(const float4*)(wr + k * 256);
      float4 u = *(const float4*)(ur + k * 256);
      acc += a.x * u.x + a.y * u.y + a.z * u.z + a.w * u.w;
    }
    #pragma unroll
    for (int off = 32; off; off >>= 1) acc += __shfl_xor(acc, off);
    if (lane == 0) R[(size_t)b * DIM + df] = fmaxf(acc + bo[df], 0.f);
  }
}

// ---------------- K5: out = LN1(U + R) ----------------
__global__ void k_ln1(const float* __restrict__ U, const float* __restrict__ R,
                      const float* __restrict__ g1, const float* __restrict__ b1,
                      float* __restrict__ out) {
  __shared__ float red[4];
  int b = blockIdx.x, tid = threadIdx.x, d0 = tid * 4;   // grid 32
  float4 u4 = *(const float4*)(U + (size_t)b * DIM + d0);
  float4 r4 = *(const float4*)(R + (size_t)b * DIM + d0);
  float x0 = u4.x + r4.x, x1 = u4.y + r4.y, x2 = u4.z + r4.z, x3 = u4.w + r4.w;
  float mu = block_sum256(x0 + x1 + x2 + x3, red) * (1.f / DIM);
  float e0 = x0 - mu, e1 = x1 - mu, e2 = x2 - mu, e3 = x3 - mu;
  float var = block_sum256(e0 * e0 + e1 * e1 + e2 * e2 + e3 * e3, red) * (1.f / DIM);
  float r = rsqrtf(var + LN_EPS);
  float4 g4 = *(const float4*)(g1 + d0);
  float4 bb4 = *(const float4*)(b1 + d0);
  float4 o;
  o.x = e0 * r * g4.x + bb4.x;
  o.y = e1 * r * g4.y + bb4.y;
  o.z = e2 * r * g4.z + bb4.z;
  o.w = e3 * r * g4.w + bb4.w;
  *(float4*)(out + (size_t)b * DIM + d0) = o;
}

extern "C" void kernel_launch(void* const* d_in, const int* in_sizes, int n_in,
                              void* d_out, int out_size, void* d_ws, size_t ws_size,
                              hipStream_t stream) {
  (void)in_sizes; (void)n_in; (void)out_size; (void)ws_size;
  const float* X  = (const float*)d_in[0];
  const int*   mask = (const int*)d_in[1];
  const float* S  = (const float*)d_in[2];
  const float* Wq = (const float*)d_in[3];
  const float* bq = (const float*)d_in[4];
  const float* Wk = (const float*)d_in[5];
  const float* bk = (const float*)d_in[6];
  const float* Wv = (const float*)d_in[7];
  const float* bv = (const float*)d_in[8];
  const float* Wo = (const float*)d_in[9];
  const float* bo = (const float*)d_in[10];
  const float* g0 = (const float*)d_in[11];
  const float* b0 = (const float*)d_in[12];
  const float* g1 = (const float*)d_in[13];
  const float* b1 = (const float*)d_in[14];
  float* out = (float*)d_out;

  char* base  = (char*)d_ws;
  size_t off = 0;
  short* Zt   = (short*)(base + off); off += (size_t)BB * PARTS * HEADS * DIM * 2;  // 8.4 MB
  short* qkbf = (short*)(base + off); off += HEADS * 1024 * 2;                      // 32 KB
  float* qb   = (float*)(base + off); off += 64;
  float* lt   = (float*)(base + off); off += (size_t)BB * PARTS * HEADS * 4;        // 16 KB
  float* lsum = (float*)(base + off); off += BB * HEADS * 4;
  int*   idx  = (int*)(base + off);   off += (size_t)BB * NN * 4;                   // 256 KB
  int*   cnt  = (int*)(base + off);   off += 256;
  float* Qp   = (float*)(base + off); off += DIM * 4;
  float* T    = (float*)(base + off); off += (size_t)BB * DIM * 4;
  float* U    = (float*)(base + off); off += (size_t)BB * DIM * 4;
  float* R    = (float*)(base + off); off += (size_t)BB * DIM * 4;

  k_front1 <<<160, 256, 0, stream>>>(mask, S, Wq, bq, Qp, idx, cnt);
  k_front2 <<<128, 128, 0, stream>>>(Qp, Wk, bk, qkbf, qb);
  k_fused8 <<<256, 512, 0, stream>>>(X, qkbf, qb, idx, cnt, Zt, lt);
  k_tov3   <<<512, 256, 0, stream>>>(Zt, lt, Wv, T, lsum);
  k_ln0    <<<32,  256, 0, stream>>>(S, T, lsum, bv, g0, b0, U);
  k_wo     <<<256, 256, 0, stream>>>(U, Wo, bo, R);
  k_ln1    <<<32,  256, 0, stream>>>(U, R, g1, b1, out);
}